// Round 11
// baseline (439.363 us; speedup 1.0000x reference)
//
#include <hip/hip_runtime.h>
#include <hip/hip_bf16.h>

#define T_TOK 2048
#define HDIM  2048
#define IDIM  1024
#define NE    16
#define NEX   17
#define NASSIGN (T_TOK*3)
#define TM    64                    // 128-row tiles: max 47 routed + 16 shared

#define G1_NWG (TM*16)              // 1024
#define G2_NWG (TM*32)              // 2048

typedef __attribute__((ext_vector_type(8))) short bf16x8;
typedef __attribute__((ext_vector_type(4))) float f32x4;

#define WAITVM0   asm volatile("s_waitcnt vmcnt(0)" ::: "memory")
#define WAITLGKM0 asm volatile("s_waitcnt lgkmcnt(0)" ::: "memory")
#define SCHEDB    __builtin_amdgcn_sched_barrier(0)
#define BARRIER   __builtin_amdgcn_s_barrier()

__device__ __forceinline__ unsigned short f2bf(float f) {
    union { float f; unsigned u; } v; v.f = f;
    unsigned r = v.u + 0x7fffu + ((v.u >> 16) & 1u);
    return (unsigned short)(r >> 16);
}
__device__ __forceinline__ unsigned pack2f(float a, float b) {
    __hip_bfloat162 h = __float22bfloat162_rn(float2{a, b});
    unsigned r;
    __builtin_memcpy(&r, &h, 4);
    return r;
}
__device__ __forceinline__ f32x4 mfma16(bf16x8 a, bf16x8 b, f32x4 c) {
    return __builtin_amdgcn_mfma_f32_16x16x32_bf16(a, b, c, 0, 0, 0);
}

// ---------------- x fp32 -> bf16 ----------------
__global__ __launch_bounds__(256) void k_cvt(const float* __restrict__ x,
                                             unsigned short* __restrict__ xbf) {
    int i = blockIdx.x * 256 + threadIdx.x;
    float4 v = ((const float4*)x)[i];
    uint2 p{pack2f(v.x, v.y), pack2f(v.z, v.w)};
    ((uint2*)xbf)[i] = p;
}

// ---------------- Router ----------------
__global__ void k_router(const float* __restrict__ x, const float* __restrict__ Wr,
                         const float* __restrict__ bias, float* __restrict__ wtok,
                         int* __restrict__ idxtok, int* __restrict__ counts) {
    int t = blockIdx.x;
    int lane = threadIdx.x & 63;
    int wave = threadIdx.x >> 6;
    __shared__ float lg[NE];
    const float4* xr = (const float4*)(x + (size_t)t * HDIM);
    for (int e = wave; e < NE; e += 4) {
        const float4* wr = (const float4*)(Wr + (size_t)e * HDIM);
        float s = 0.f;
        for (int j = lane; j < HDIM / 4; j += 64) {
            float4 a = xr[j], b = wr[j];
            s += a.x*b.x + a.y*b.y + a.z*b.z + a.w*b.w;
        }
        #pragma unroll
        for (int d = 32; d; d >>= 1) s += __shfl_xor(s, d);
        if (lane == 0) lg[e] = s + bias[e];
    }
    __syncthreads();
    if (threadIdx.x == 0) {
        float m = lg[0];
        #pragma unroll
        for (int e = 1; e < NE; e++) m = fmaxf(m, lg[e]);
        float p[NE]; float S = 0.f;
        #pragma unroll
        for (int e = 0; e < NE; e++) { p[e] = expf(lg[e] - m); S += p[e]; }
        int i0 = 0;
        #pragma unroll
        for (int e = 1; e < NE; e++) if (p[e] > p[i0]) i0 = e;
        int i1 = (i0 == 0) ? 1 : 0;
        for (int e = 0; e < NE; e++) if (e != i0 && p[e] > p[i1]) i1 = e;
        float v0 = p[i0] / S, v1 = p[i1] / S;
        float wsum = v0 + v1 + 1e-9f;
        wtok[t*2+0] = v0 / wsum;
        wtok[t*2+1] = v1 / wsum;
        idxtok[t*2+0] = i0;
        idxtok[t*2+1] = i1;
        atomicAdd(&counts[i0], 1);
        atomicAdd(&counts[i1], 1);
    }
}

// ---------------- scan + tile work-list ----------------
__global__ void k_scan(const int* __restrict__ counts, int* __restrict__ offs,
                       int* __restrict__ cursor, int4* __restrict__ tiles) {
    if (threadIdx.x == 0) {
        int acc = 0;
        for (int e = 0; e < NEX; e++) {
            offs[e] = acc; cursor[e] = acc;
            acc += (e < NE) ? counts[e] : T_TOK;
        }
        offs[NEX] = acc;
        int nt = 0;
        for (int e = 0; e < NEX; e++) {
            for (int r = offs[e]; r < offs[e+1]; r += 128) {
                tiles[nt] = int4{r, min(128, offs[e+1] - r), e, 0};
                nt++;
            }
        }
        for (; nt < TM; nt++) tiles[nt] = int4{0, 0, 0, 0};
    }
}

__global__ void k_scatter(const int* __restrict__ idxtok, const float* __restrict__ wtok,
                          int* __restrict__ cursor, const int* __restrict__ offs,
                          int* __restrict__ rows, float* __restrict__ wrow) {
    int t = blockIdx.x * blockDim.x + threadIdx.x;
    if (t >= T_TOK) return;
    #pragma unroll
    for (int k = 0; k < 2; k++) {
        int e = idxtok[t*2+k];
        int pos = atomicAdd(&cursor[e], 1);
        rows[pos] = t;
        wrow[pos] = wtok[t*2+k];
    }
    int p16 = offs[NE] + t;
    rows[p16] = t;
    wrow[p16] = 1.0f;
}

// ---------------- GEMM1: act = w * silu(X@Wg) * (X@Wu) -> bf16 ----------------
// tile 128x64, BK=32, NK=64, 512 thr (8 waves 4x2, wave-tile 32x32).
// A-frags straight from global (L2/LLC); only W tiles in LDS (dbuf, 80B rows).
// One s_barrier per K-step.
__global__ __launch_bounds__(512) void k_gemm1(
        const unsigned short* __restrict__ xbf,
        const float* __restrict__ Wg, const float* __restrict__ Wu,
        const float* __restrict__ sWg, const float* __restrict__ sWu,
        const int4* __restrict__ tiles, const int* __restrict__ rows,
        const float* __restrict__ wrow, unsigned short* __restrict__ act) {
    int bid = blockIdx.x;
    int wg = (bid & 7) * (G1_NWG >> 3) + (bid >> 3);   // XCD-chunked
    int ti = wg & (TM - 1);
    int ct = wg >> 6;

    int4 tl = tiles[ti];
    int nrows = tl.y;
    if (nrows == 0) return;
    int rs = tl.x, e = tl.z;
    const float* wgp = (e < NE) ? Wg + (size_t)e * HDIM * IDIM : sWg;
    const float* wup = (e < NE) ? Wu + (size_t)e * HDIM * IDIM : sWu;
    int n0 = ct * 64;

    __shared__ unsigned short Bs[2][64 * 40];   // [n][32k] rows padded to 80B
    __shared__ unsigned short Us[2][64 * 40];
    __shared__ int rloc[128];

    int tid = threadIdx.x;
    if (tid < 128) rloc[tid] = rows[rs + min(tid, nrows - 1)];
    __syncthreads();

    int l = tid & 63, w = tid >> 6;
    int wr = (w >> 1) << 5;      // 0,32,64,96
    int wc = (w & 1) << 5;       // 0,32
    int fr = l & 15;
    int fk = (l >> 4) << 3;      // 0,8,16,24

    const unsigned short* ap0 = xbf + (size_t)rloc[wr + fr] * HDIM + fk;
    const unsigned short* ap1 = xbf + (size_t)rloc[wr + 16 + fr] * HDIM + fk;

    // W staging: thread covers n2,n2+1 at k-rows kb,kb+1
    int n2 = (tid & 31) << 1;
    int kb = (tid >> 5) << 1;    // 0..30
    const float* gsrc = wgp + (size_t)kb * IDIM + n0 + n2;
    const float* usrc = wup + (size_t)kb * IDIM + n0 + n2;
    int wb0 = n2 * 80 + kb * 2;
    int wb1 = wb0 + 80;

    int ro0 = (wc + fr) * 80 + fk * 2;
    int ro1 = (wc + 16 + fr) * 80 + fk * 2;

    float2 g0, g1, u0, u1;
    bf16x8 aP0, aP1, aQ0, aQ1;
    f32x4 accg[2][2] = {}, accu[2][2] = {};

    const int NK = HDIM / 32;
    const int KL = (NK - 1) * 32;

    #define G1_LOADW(KE) do { \
        g0 = *(const float2*)(gsrc + (size_t)(KE) * IDIM); \
        g1 = *(const float2*)(gsrc + (size_t)(KE) * IDIM + IDIM); \
        u0 = *(const float2*)(usrc + (size_t)(KE) * IDIM); \
        u1 = *(const float2*)(usrc + (size_t)(KE) * IDIM + IDIM); \
    } while (0)
    #define G1_WRITEW(B) do { \
        *(unsigned*)((char*)Bs[B] + wb0) = pack2f(g0.x, g1.x); \
        *(unsigned*)((char*)Bs[B] + wb1) = pack2f(g0.y, g1.y); \
        *(unsigned*)((char*)Us[B] + wb0) = pack2f(u0.x, u1.x); \
        *(unsigned*)((char*)Us[B] + wb1) = pack2f(u0.y, u1.y); \
    } while (0)
    #define G1_COMPUTE(B, A0, A1) do { \
        bf16x8 b0 = *(const bf16x8*)((const char*)Bs[B] + ro0); \
        bf16x8 v0 = *(const bf16x8*)((const char*)Us[B] + ro0); \
        accg[0][0] = mfma16(A0, b0, accg[0][0]); \
        accg[1][0] = mfma16(A1, b0, accg[1][0]); \
        accu[0][0] = mfma16(A0, v0, accu[0][0]); \
        accu[1][0] = mfma16(A1, v0, accu[1][0]); \
        bf16x8 b1 = *(const bf16x8*)((const char*)Bs[B] + ro1); \
        bf16x8 v1 = *(const bf16x8*)((const char*)Us[B] + ro1); \
        accg[0][1] = mfma16(A0, b1, accg[0][1]); \
        accg[1][1] = mfma16(A1, b1, accg[1][1]); \
        accu[0][1] = mfma16(A0, v1, accu[0][1]); \
        accu[1][1] = mfma16(A1, v1, accu[1][1]); \
    } while (0)

    // prologue: W(0) staged in buf0; A(0)->P; W(1) in regs
    G1_LOADW(0);
    G1_WRITEW(0);            // compiler inserts vmcnt wait
    aP0 = *(const bf16x8*)(ap0);
    aP1 = *(const bf16x8*)(ap1);
    G1_LOADW(32);
    WAITLGKM0;
    BARRIER;
    SCHEDB;

    for (int k = 0; k < NK; k += 2) {
        {   // step k: A=P, read buf0, write buf1 (W(k+1))
            int kA = min(k + 1, NK - 1) * 32;
            int kW = min(k + 2, NK - 1) * 32;
            G1_WRITEW(1);
            aQ0 = *(const bf16x8*)(ap0 + kA);
            aQ1 = *(const bf16x8*)(ap1 + kA);
            G1_LOADW(kW);
            SCHEDB;
            G1_COMPUTE(0, aP0, aP1);
            SCHEDB;
            WAITLGKM0;
            BARRIER;
            SCHEDB;
        }
        {   // step k+1: A=Q, read buf1, write buf0 (W(k+2))
            int kA = min(k + 2, NK - 1) * 32;
            int kW = min(k + 3, NK - 1) * 32;
            G1_WRITEW(0);
            aP0 = *(const bf16x8*)(ap0 + kA);
            aP1 = *(const bf16x8*)(ap1 + kA);
            G1_LOADW(kW);
            SCHEDB;
            G1_COMPUTE(1, aQ0, aQ1);
            SCHEDB;
            WAITLGKM0;
            BARRIER;
            SCHEDB;
        }
    }
    WAITVM0;

    int crow = (l >> 4) << 2;
    int ccol = l & 15;
    #pragma unroll
    for (int m = 0; m < 2; ++m) {
        #pragma unroll
        for (int reg = 0; reg < 4; ++reg) {
            int r = wr + m * 16 + crow + reg;
            if (r < nrows) {
                float wv = wrow[rs + r];
                #pragma unroll
                for (int n = 0; n < 2; ++n) {
                    float g = accg[m][n][reg], u = accu[m][n][reg];
                    act[(size_t)(rs + r) * IDIM + n0 + wc + n * 16 + ccol] =
                        f2bf(g / (1.f + __expf(-g)) * u * wv);
                }
            }
        }
    }
    #undef G1_LOADW
    #undef G1_WRITEW
    #undef G1_COMPUTE
}

// ---------------- GEMM2: out[tok] += act @ Wd ----------------
// tile 128x64, BK=32, NK=32, 512 thr. A from act (global, LLC). W LDS dbuf.
__global__ __launch_bounds__(512) void k_gemm2(
        const unsigned short* __restrict__ act,
        const float* __restrict__ Wd, const float* __restrict__ sWd,
        const int4* __restrict__ tiles, const int* __restrict__ rows,
        float* __restrict__ out) {
    int bid = blockIdx.x;
    int wg = (bid & 7) * (G2_NWG >> 3) + (bid >> 3);
    int ti = wg & (TM - 1);
    int ct = wg >> 6;

    int4 tl = tiles[ti];
    int nrows = tl.y;
    if (nrows == 0) return;
    int rs = tl.x, e = tl.z;
    const float* wdp = (e < NE) ? Wd + (size_t)e * IDIM * HDIM : sWd;
    int n0 = ct * 64;

    __shared__ unsigned short Bs[2][64 * 40];

    int tid = threadIdx.x;
    int l = tid & 63, w = tid >> 6;
    int wr = (w >> 1) << 5;
    int wc = (w & 1) << 5;
    int fr = l & 15;
    int fk = (l >> 4) << 3;

    const unsigned short* ap0 = act + (size_t)(rs + min(wr + fr, nrows - 1)) * IDIM + fk;
    const unsigned short* ap1 = act + (size_t)(rs + min(wr + 16 + fr, nrows - 1)) * IDIM + fk;

    int n2 = (tid & 31) << 1;
    int kb = (tid >> 5) << 1;
    const float* dsrc = wdp + (size_t)kb * HDIM + n0 + n2;
    int wb0 = n2 * 80 + kb * 2;
    int wb1 = wb0 + 80;

    int ro0 = (wc + fr) * 80 + fk * 2;
    int ro1 = (wc + 16 + fr) * 80 + fk * 2;

    float2 d0, d1;
    bf16x8 aP0, aP1, aQ0, aQ1;
    f32x4 acc[2][2] = {};

    const int NK = IDIM / 32;

    #define G2_LOADW(KE) do { \
        d0 = *(const float2*)(dsrc + (size_t)(KE) * HDIM); \
        d1 = *(const float2*)(dsrc + (size_t)(KE) * HDIM + HDIM); \
    } while (0)
    #define G2_WRITEW(B) do { \
        *(unsigned*)((char*)Bs[B] + wb0) = pack2f(d0.x, d1.x); \
        *(unsigned*)((char*)Bs[B] + wb1) = pack2f(d0.y, d1.y); \
    } while (0)
    #define G2_COMPUTE(B, A0, A1) do { \
        bf16x8 b0 = *(const bf16x8*)((const char*)Bs[B] + ro0); \
        acc[0][0] = mfma16(A0, b0, acc[0][0]); \
        acc[1][0] = mfma16(A1, b0, acc[1][0]); \
        bf16x8 b1 = *(const bf16x8*)((const char*)Bs[B] + ro1); \
        acc[0][1] = mfma16(A0, b1, acc[0][1]); \
        acc[1][1] = mfma16(A1, b1, acc[1][1]); \
    } while (0)

    G2_LOADW(0);
    G2_WRITEW(0);
    aP0 = *(const bf16x8*)(ap0);
    aP1 = *(const bf16x8*)(ap1);
    G2_LOADW(32);
    WAITLGKM0;
    BARRIER;
    SCHEDB;

    for (int k = 0; k < NK; k += 2) {
        {
            int kA = min(k + 1, NK - 1) * 32;
            int kW = min(k + 2, NK - 1) * 32;
            G2_WRITEW(1);
            aQ0 = *(const bf16x8*)(ap0 + kA);
            aQ1 = *(const bf16x8*)(ap1 + kA);
            G2_LOADW(kW);
            SCHEDB;
            G2_COMPUTE(0, aP0, aP1);
            SCHEDB;
            WAITLGKM0;
            BARRIER;
            SCHEDB;
        }
        {
            int kA = min(k + 2, NK - 1) * 32;
            int kW = min(k + 3, NK - 1) * 32;
            G2_WRITEW(0);
            aP0 = *(const bf16x8*)(ap0 + kA);
            aP1 = *(const bf16x8*)(ap1 + kA);
            G2_LOADW(kW);
            SCHEDB;
            G2_COMPUTE(1, aQ0, aQ1);
            SCHEDB;
            WAITLGKM0;
            BARRIER;
            SCHEDB;
        }
    }
    WAITVM0;

    int crow = (l >> 4) << 2;
    int ccol = l & 15;
    #pragma unroll
    for (int m = 0; m < 2; ++m) {
        #pragma unroll
        for (int reg = 0; reg < 4; ++reg) {
            int r = wr + m * 16 + crow + reg;
            if (r < nrows) {
                size_t base = (size_t)rows[rs + r] * HDIM + n0 + wc + ccol;
                atomicAdd(&out[base], acc[m][0][reg]);
                atomicAdd(&out[base + 16], acc[m][1][reg]);
            }
        }
    }
    #undef G2_LOADW
    #undef G2_WRITEW
    #undef G2_COMPUTE
}

extern "C" void kernel_launch(void* const* d_in, const int* in_sizes, int n_in,
                              void* d_out, int out_size, void* d_ws, size_t ws_size,
                              hipStream_t stream) {
    const float* x    = (const float*)d_in[0];
    const float* Wr   = (const float*)d_in[1];
    const float* bias = (const float*)d_in[2];
    const float* Wg   = (const float*)d_in[3];
    const float* Wu   = (const float*)d_in[4];
    const float* Wd   = (const float*)d_in[5];
    const float* sWg  = (const float*)d_in[6];
    const float* sWu  = (const float*)d_in[7];
    const float* sWd  = (const float*)d_in[8];
    float* out = (float*)d_out;

    char* p = (char*)d_ws;
    int*   counts = (int*)p;                 p += 256;
    int*   offs   = (int*)p;                 p += 256;
    int*   cursor = (int*)p;                 p += 256;
    int4*  tiles  = (int4*)p;                p += TM * sizeof(int4);
    int*   idxtok = (int*)p;                 p += (size_t)T_TOK * 2 * sizeof(int);
    float* wtok   = (float*)p;               p += (size_t)T_TOK * 2 * sizeof(float);
    int*   rows   = (int*)p;                 p += (size_t)NASSIGN * sizeof(int);
    float* wrow   = (float*)p;               p += (size_t)NASSIGN * sizeof(float);
    unsigned short* act = (unsigned short*)p; p += (size_t)NASSIGN * IDIM * sizeof(unsigned short);
    unsigned short* xbf = (unsigned short*)p; // 8.4MB

    hipMemsetAsync(counts, 0, 256, stream);
    hipMemsetAsync(d_out, 0, (size_t)out_size * sizeof(float), stream);

    k_cvt<<<dim3(T_TOK * HDIM / 1024), dim3(256), 0, stream>>>(x, xbf);
    k_router<<<dim3(T_TOK), dim3(256), 0, stream>>>(x, Wr, bias, wtok, idxtok, counts);
    k_scan<<<dim3(1), dim3(64), 0, stream>>>(counts, offs, cursor, tiles);
    k_scatter<<<dim3((T_TOK + 255) / 256), dim3(256), 0, stream>>>(idxtok, wtok, cursor, offs, rows, wrow);
    k_gemm1<<<dim3(G1_NWG), dim3(512), 0, stream>>>(xbf, Wg, Wu, sWg, sWu, tiles, rows, wrow, act);
    k_gemm2<<<dim3(G2_NWG), dim3(512), 0, stream>>>(act, Wd, sWd, tiles, rows, out);
}

// Round 13
// 416.169 us; speedup vs baseline: 1.0557x; 1.0557x over previous
//
#include <hip/hip_runtime.h>
#include <hip/hip_bf16.h>

#define T_TOK 2048
#define HDIM  2048
#define IDIM  1024
#define NE    16
#define NEX   17
#define NASSIGN (T_TOK*3)
#define TM    64                    // 128-row tiles: max 47 routed + 16 shared

#define G1_NWG (TM*16)              // 1024
#define G2_NWG (TM*32)              // 2048

typedef __attribute__((ext_vector_type(8))) short bf16x8;
typedef __attribute__((ext_vector_type(4))) float f32x4;

__device__ __forceinline__ unsigned short f2bf(float f) {
    union { float f; unsigned u; } v; v.f = f;
    unsigned r = v.u + 0x7fffu + ((v.u >> 16) & 1u);
    return (unsigned short)(r >> 16);
}
__device__ __forceinline__ unsigned pack2f(float a, float b) {
    __hip_bfloat162 h = __float22bfloat162_rn(float2{a, b});
    unsigned r;
    __builtin_memcpy(&r, &h, 4);
    return r;
}
// swizzle for 64B LDS rows (32 bf16): 4 chunks of 16B, slot = (k>>3) ^ ((row>>1)&3)
__device__ __forceinline__ int SW2(int r) { return (r >> 1) & 3; }
__device__ __forceinline__ int lds_off32(int row, int kelem) {
    return (row << 6) + ((((kelem >> 3) ^ SW2(row))) << 4) + ((kelem & 7) << 1);
}
__device__ __forceinline__ f32x4 mfma16(bf16x8 a, bf16x8 b, f32x4 c) {
    return __builtin_amdgcn_mfma_f32_16x16x32_bf16(a, b, c, 0, 0, 0);
}
__device__ __forceinline__ void gload_lds16(const void* g, void* lds) {
    __builtin_amdgcn_global_load_lds(
        (const __attribute__((address_space(1))) unsigned*)g,
        (__attribute__((address_space(3))) unsigned*)lds, 16, 0, 0);
}

// ---------------- x fp32 -> bf16 ----------------
__global__ __launch_bounds__(256) void k_cvt(const float* __restrict__ x,
                                             unsigned short* __restrict__ xbf) {
    int i = blockIdx.x * 256 + threadIdx.x;
    float4 v = ((const float4*)x)[i];
    uint2 p{pack2f(v.x, v.y), pack2f(v.z, v.w)};
    ((uint2*)xbf)[i] = p;
}

// ---------------- Router ----------------
__global__ void k_router(const float* __restrict__ x, const float* __restrict__ Wr,
                         const float* __restrict__ bias, float* __restrict__ wtok,
                         int* __restrict__ idxtok, int* __restrict__ counts) {
    int t = blockIdx.x;
    int lane = threadIdx.x & 63;
    int wave = threadIdx.x >> 6;
    __shared__ float lg[NE];
    const float4* xr = (const float4*)(x + (size_t)t * HDIM);
    for (int e = wave; e < NE; e += 4) {
        const float4* wr = (const float4*)(Wr + (size_t)e * HDIM);
        float s = 0.f;
        for (int j = lane; j < HDIM / 4; j += 64) {
            float4 a = xr[j], b = wr[j];
            s += a.x*b.x + a.y*b.y + a.z*b.z + a.w*b.w;
        }
        #pragma unroll
        for (int d = 32; d; d >>= 1) s += __shfl_xor(s, d);
        if (lane == 0) lg[e] = s + bias[e];
    }
    __syncthreads();
    if (threadIdx.x == 0) {
        float m = lg[0];
        #pragma unroll
        for (int e = 1; e < NE; e++) m = fmaxf(m, lg[e]);
        float p[NE]; float S = 0.f;
        #pragma unroll
        for (int e = 0; e < NE; e++) { p[e] = expf(lg[e] - m); S += p[e]; }
        int i0 = 0;
        #pragma unroll
        for (int e = 1; e < NE; e++) if (p[e] > p[i0]) i0 = e;
        int i1 = (i0 == 0) ? 1 : 0;
        for (int e = 0; e < NE; e++) if (e != i0 && p[e] > p[i1]) i1 = e;
        float v0 = p[i0] / S, v1 = p[i1] / S;
        float wsum = v0 + v1 + 1e-9f;
        wtok[t*2+0] = v0 / wsum;
        wtok[t*2+1] = v1 / wsum;
        idxtok[t*2+0] = i0;
        idxtok[t*2+1] = i1;
        atomicAdd(&counts[i0], 1);
        atomicAdd(&counts[i1], 1);
    }
}

// ---------------- scan + tile work-list ----------------
__global__ void k_scan(const int* __restrict__ counts, int* __restrict__ offs,
                       int* __restrict__ cursor, int4* __restrict__ tiles) {
    if (threadIdx.x == 0) {
        int acc = 0;
        for (int e = 0; e < NEX; e++) {
            offs[e] = acc; cursor[e] = acc;
            acc += (e < NE) ? counts[e] : T_TOK;
        }
        offs[NEX] = acc;
        int nt = 0;
        for (int e = 0; e < NEX; e++) {
            for (int r = offs[e]; r < offs[e+1]; r += 128) {
                tiles[nt] = int4{r, min(128, offs[e+1] - r), e, 0};
                nt++;
            }
        }
        for (; nt < TM; nt++) tiles[nt] = int4{0, 0, 0, 0};
    }
}

__global__ void k_scatter(const int* __restrict__ idxtok, const float* __restrict__ wtok,
                          int* __restrict__ cursor, const int* __restrict__ offs,
                          int* __restrict__ rows, float* __restrict__ wrow) {
    int t = blockIdx.x * blockDim.x + threadIdx.x;
    if (t >= T_TOK) return;
    #pragma unroll
    for (int k = 0; k < 2; k++) {
        int e = idxtok[t*2+k];
        int pos = atomicAdd(&cursor[e], 1);
        rows[pos] = t;
        wrow[pos] = wtok[t*2+k];
    }
    int p16 = offs[NE] + t;
    rows[p16] = t;
    wrow[p16] = 1.0f;
}

// ---------------- GEMM1: act = w * silu(X@Wg) * (X@Wu) -> bf16 ----------------
// tile 128x64, BK=32, NK=64, 512 thr (8 waves 2x4). LDS 33KB -> 4 blocks/CU.
// A via gload_lds (pre-swizzled src, dbuf); W reg-staged 1 step ahead (dbuf).
// One __syncthreads per K-step. KE args to LOADW are STEP indices (x32 inside).
__global__ __launch_bounds__(512) void k_gemm1(
        const unsigned short* __restrict__ xbf,
        const float* __restrict__ Wg, const float* __restrict__ Wu,
        const float* __restrict__ sWg, const float* __restrict__ sWu,
        const int4* __restrict__ tiles, const int* __restrict__ rows,
        const float* __restrict__ wrow, unsigned short* __restrict__ act) {
    int bid = blockIdx.x;
    int wg = (bid & 7) * (G1_NWG >> 3) + (bid >> 3);   // XCD-chunked
    int ti = wg & (TM - 1);
    int ct = wg >> 6;

    int4 tl = tiles[ti];
    int nrows = tl.y;
    if (nrows == 0) return;
    int rs = tl.x, e = tl.z;
    const float* wgp = (e < NE) ? Wg + (size_t)e * HDIM * IDIM : sWg;
    const float* wup = (e < NE) ? Wu + (size_t)e * HDIM * IDIM : sWu;
    int n0 = ct * 64;

    __shared__ unsigned short As[2][128 * 32];   // 16 KB
    __shared__ unsigned short Bs[2][64 * 32];    // 8 KB
    __shared__ unsigned short Us[2][64 * 32];    // 8 KB
    __shared__ int rloc[128];

    int tid = threadIdx.x;
    if (tid < 128) rloc[tid] = rows[rs + min(tid, nrows - 1)];
    __syncthreads();

    int l = tid & 63, w = tid >> 6;
    // A DMA: wave w covers rows w*16..w*16+15 (1KB); lane: row=w*16+(l>>2), chunk=l&3.
    // source chunk pre-swizzled so linear DMA dest matches swizzled reads.
    int arow = w * 16 + (l >> 2);
    const unsigned short* asrc =
        xbf + (size_t)rloc[arow] * HDIM + (((l & 3) ^ SW2(arow)) << 3);

    // W staging: thread covers n2,n2+1 at k-rows kb,kb+1 (4 elems per matrix)
    int n2 = (tid & 31) << 1;
    int kb = (tid >> 5) << 1;
    const float* gsrc = wgp + (size_t)kb * IDIM + n0 + n2;
    const float* usrc = wup + (size_t)kb * IDIM + n0 + n2;
    int wo0 = lds_off32(n2, kb);
    int wo1 = lds_off32(n2 + 1, kb);

    int wr = (w >> 2) << 6;      // 0/64
    int wc = (w & 3) << 4;       // 0/16/32/48
    int fr = l & 15;
    int fk = (l >> 4) << 3;

    float2 g0, g1, u0, u1;
    f32x4 accg[4] = {}, accu[4] = {};
    const int NK = HDIM / 32;

    #define G1_LOADW(KE) do { \
        const float* gp_ = gsrc + (size_t)(KE) * 32 * IDIM; \
        const float* up_ = usrc + (size_t)(KE) * 32 * IDIM; \
        g0 = *(const float2*)(gp_); \
        g1 = *(const float2*)(gp_ + IDIM); \
        u0 = *(const float2*)(up_); \
        u1 = *(const float2*)(up_ + IDIM); \
    } while (0)
    #define G1_WRITEW(B) do { \
        *(unsigned*)((char*)Bs[B] + wo0) = pack2f(g0.x, g1.x); \
        *(unsigned*)((char*)Bs[B] + wo1) = pack2f(g0.y, g1.y); \
        *(unsigned*)((char*)Us[B] + wo0) = pack2f(u0.x, u1.x); \
        *(unsigned*)((char*)Us[B] + wo1) = pack2f(u0.y, u1.y); \
    } while (0)
    #define G1_MFMA(B) do { \
        bf16x8 a0 = *(const bf16x8*)((const char*)As[B] + lds_off32(wr + fr, fk)); \
        bf16x8 a1 = *(const bf16x8*)((const char*)As[B] + lds_off32(wr + 16 + fr, fk)); \
        bf16x8 a2 = *(const bf16x8*)((const char*)As[B] + lds_off32(wr + 32 + fr, fk)); \
        bf16x8 a3 = *(const bf16x8*)((const char*)As[B] + lds_off32(wr + 48 + fr, fk)); \
        bf16x8 bg = *(const bf16x8*)((const char*)Bs[B] + lds_off32(wc + fr, fk)); \
        bf16x8 bu = *(const bf16x8*)((const char*)Us[B] + lds_off32(wc + fr, fk)); \
        accg[0] = mfma16(a0, bg, accg[0]);  accu[0] = mfma16(a0, bu, accu[0]); \
        accg[1] = mfma16(a1, bg, accg[1]);  accu[1] = mfma16(a1, bu, accu[1]); \
        accg[2] = mfma16(a2, bg, accg[2]);  accu[2] = mfma16(a2, bu, accu[2]); \
        accg[3] = mfma16(a3, bg, accg[3]);  accu[3] = mfma16(a3, bu, accu[3]); \
    } while (0)

    // prologue
    G1_LOADW(0);
    G1_WRITEW(0);                 // compiler waits the regs
    gload_lds16(asrc, (char*)As[0] + w * 1024);
    G1_LOADW(1);                  // W(1) regs for next write
    __syncthreads();              // drains DMA + LDS

    for (int k = 0; k < NK; ++k) {
        int buf = k & 1;
        if (k + 1 < NK) {
            G1_WRITEW(buf ^ 1);                                   // W(k+1)
            gload_lds16(asrc + (k + 1) * 32, (char*)As[buf ^ 1] + w * 1024);
            G1_LOADW(min(k + 2, NK - 1));                         // W(k+2) regs
        }
        G1_MFMA(buf);
        __syncthreads();
    }

    int crow = (l >> 4) << 2;
    int ccol = l & 15;
    #pragma unroll
    for (int m = 0; m < 4; ++m) {
        #pragma unroll
        for (int reg = 0; reg < 4; ++reg) {
            int r = wr + m * 16 + crow + reg;
            if (r < nrows) {
                float wv = wrow[rs + r];
                float g = accg[m][reg], u = accu[m][reg];
                act[(size_t)(rs + r) * IDIM + n0 + wc + ccol] =
                    f2bf(g / (1.f + __expf(-g)) * u * wv);
            }
        }
    }
    #undef G1_LOADW
    #undef G1_WRITEW
    #undef G1_MFMA
}

// ---------------- GEMM2: out[tok] += act @ Wd ----------------
// tile 128x64, BK=32, NK=32, 512 thr. LDS 24.5KB.
__global__ __launch_bounds__(512) void k_gemm2(
        const unsigned short* __restrict__ act,
        const float* __restrict__ Wd, const float* __restrict__ sWd,
        const int4* __restrict__ tiles, const int* __restrict__ rows,
        float* __restrict__ out) {
    int bid = blockIdx.x;
    int wg = (bid & 7) * (G2_NWG >> 3) + (bid >> 3);
    int ti = wg & (TM - 1);
    int ct = wg >> 6;

    int4 tl = tiles[ti];
    int nrows = tl.y;
    if (nrows == 0) return;
    int rs = tl.x, e = tl.z;
    const float* wdp = (e < NE) ? Wd + (size_t)e * IDIM * HDIM : sWd;
    int n0 = ct * 64;

    __shared__ unsigned short As[2][128 * 32];   // 16 KB
    __shared__ unsigned short Bs[2][64 * 32];    // 8 KB

    int tid = threadIdx.x;
    int l = tid & 63, w = tid >> 6;
    int arow = w * 16 + (l >> 2);
    const unsigned short* asrc =
        act + (size_t)(rs + min(arow, nrows - 1)) * IDIM + (((l & 3) ^ SW2(arow)) << 3);

    int n2 = (tid & 31) << 1;
    int kb = (tid >> 5) << 1;
    const float* dsrc = wdp + (size_t)kb * HDIM + n0 + n2;
    int wo0 = lds_off32(n2, kb);
    int wo1 = lds_off32(n2 + 1, kb);

    int wr = (w >> 2) << 6;
    int wc = (w & 3) << 4;
    int fr = l & 15;
    int fk = (l >> 4) << 3;

    float2 d0, d1;
    f32x4 acc[4] = {};
    const int NK = IDIM / 32;

    #define G2_LOADW(KE) do { \
        const float* dp_ = dsrc + (size_t)(KE) * 32 * HDIM; \
        d0 = *(const float2*)(dp_); \
        d1 = *(const float2*)(dp_ + HDIM); \
    } while (0)
    #define G2_WRITEW(B) do { \
        *(unsigned*)((char*)Bs[B] + wo0) = pack2f(d0.x, d1.x); \
        *(unsigned*)((char*)Bs[B] + wo1) = pack2f(d0.y, d1.y); \
    } while (0)
    #define G2_MFMA(B) do { \
        bf16x8 a0 = *(const bf16x8*)((const char*)As[B] + lds_off32(wr + fr, fk)); \
        bf16x8 a1 = *(const bf16x8*)((const char*)As[B] + lds_off32(wr + 16 + fr, fk)); \
        bf16x8 a2 = *(const bf16x8*)((const char*)As[B] + lds_off32(wr + 32 + fr, fk)); \
        bf16x8 a3 = *(const bf16x8*)((const char*)As[B] + lds_off32(wr + 48 + fr, fk)); \
        bf16x8 b  = *(const bf16x8*)((const char*)Bs[B] + lds_off32(wc + fr, fk)); \
        acc[0] = mfma16(a0, b, acc[0]); \
        acc[1] = mfma16(a1, b, acc[1]); \
        acc[2] = mfma16(a2, b, acc[2]); \
        acc[3] = mfma16(a3, b, acc[3]); \
    } while (0)

    G2_LOADW(0);
    G2_WRITEW(0);
    gload_lds16(asrc, (char*)As[0] + w * 1024);
    G2_LOADW(1);
    __syncthreads();

    for (int k = 0; k < NK; ++k) {
        int buf = k & 1;
        if (k + 1 < NK) {
            G2_WRITEW(buf ^ 1);
            gload_lds16(asrc + (k + 1) * 32, (char*)As[buf ^ 1] + w * 1024);
            G2_LOADW(min(k + 2, NK - 1));
        }
        G2_MFMA(buf);
        __syncthreads();
    }

    int crow = (l >> 4) << 2;
    int ccol = l & 15;
    #pragma unroll
    for (int m = 0; m < 4; ++m) {
        #pragma unroll
        for (int reg = 0; reg < 4; ++reg) {
            int r = wr + m * 16 + crow + reg;
            if (r < nrows) {
                atomicAdd(&out[(size_t)rows[rs + r] * HDIM + n0 + wc + ccol], acc[m][reg]);
            }
        }
    }
    #undef G2_LOADW
    #undef G2_WRITEW
    #undef G2_MFMA
}

extern "C" void kernel_launch(void* const* d_in, const int* in_sizes, int n_in,
                              void* d_out, int out_size, void* d_ws, size_t ws_size,
                              hipStream_t stream) {
    const float* x    = (const float*)d_in[0];
    const float* Wr   = (const float*)d_in[1];
    const float* bias = (const float*)d_in[2];
    const float* Wg   = (const float*)d_in[3];
    const float* Wu   = (const float*)d_in[4];
    const float* Wd   = (const float*)d_in[5];
    const float* sWg  = (const float*)d_in[6];
    const float* sWu  = (const float*)d_in[7];
    const float* sWd  = (const float*)d_in[8];
    float* out = (float*)d_out;

    char* p = (char*)d_ws;
    int*   counts = (int*)p;                 p += 256;
    int*   offs   = (int*)p;                 p += 256;
    int*   cursor = (int*)p;                 p += 256;
    int4*  tiles  = (int4*)p;                p += TM * sizeof(int4);
    int*   idxtok = (int*)p;                 p += (size_t)T_TOK * 2 * sizeof(int);
    float* wtok   = (float*)p;               p += (size_t)T_TOK * 2 * sizeof(float);
    int*   rows   = (int*)p;                 p += (size_t)NASSIGN * sizeof(int);
    float* wrow   = (float*)p;               p += (size_t)NASSIGN * sizeof(float);
    unsigned short* act = (unsigned short*)p; p += (size_t)NASSIGN * IDIM * sizeof(unsigned short);
    unsigned short* xbf = (unsigned short*)p; // 8.4MB

    hipMemsetAsync(counts, 0, 256, stream);
    hipMemsetAsync(d_out, 0, (size_t)out_size * sizeof(float), stream);

    k_cvt<<<dim3(T_TOK * HDIM / 1024), dim3(256), 0, stream>>>(x, xbf);
    k_router<<<dim3(T_TOK), dim3(256), 0, stream>>>(x, Wr, bias, wtok, idxtok, counts);
    k_scan<<<dim3(1), dim3(64), 0, stream>>>(counts, offs, cursor, tiles);
    k_scatter<<<dim3((T_TOK + 255) / 256), dim3(256), 0, stream>>>(idxtok, wtok, cursor, offs, rows, wrow);
    k_gemm1<<<dim3(G1_NWG), dim3(512), 0, stream>>>(xbf, Wg, Wu, sWg, sWu, tiles, rows, wrow, act);
    k_gemm2<<<dim3(G2_NWG), dim3(512), 0, stream>>>(act, Wd, sWd, tiles, rows, out);
}

// Round 14
// 353.638 us; speedup vs baseline: 1.2424x; 1.1768x over previous
//
#include <hip/hip_runtime.h>
#include <hip/hip_bf16.h>

#define T_TOK 2048
#define HDIM  2048
#define IDIM  1024
#define NE    16
#define NEX   17
#define NASSIGN (T_TOK*3)
#define TM    64                    // 128-row tiles: max 47 routed + 16 shared

#define G1_NWG (TM*16)              // 1024
#define G2_NWG (TM*32)              // 2048

typedef __attribute__((ext_vector_type(8))) short bf16x8;
typedef __attribute__((ext_vector_type(4))) float f32x4;

#define WAITVM(N) asm volatile("s_waitcnt vmcnt(" #N ")" ::: "memory")
#define WAITLGKM0 asm volatile("s_waitcnt lgkmcnt(0)" ::: "memory")
#define SCHEDB    __builtin_amdgcn_sched_barrier(0)
#define BARRIER   __builtin_amdgcn_s_barrier()

__device__ __forceinline__ unsigned short f2bf(float f) {
    union { float f; unsigned u; } v; v.f = f;
    unsigned r = v.u + 0x7fffu + ((v.u >> 16) & 1u);
    return (unsigned short)(r >> 16);
}
__device__ __forceinline__ unsigned pack2f(float a, float b) {
    __hip_bfloat162 h = __float22bfloat162_rn(float2{a, b});
    unsigned r;
    __builtin_memcpy(&r, &h, 4);
    return r;
}
// swizzle for 64B LDS rows (32 bf16): 4 chunks of 16B, slot = (k>>3) ^ ((row>>1)&3)
__device__ __forceinline__ int SW2(int r) { return (r >> 1) & 3; }
__device__ __forceinline__ int lds_off32(int row, int kelem) {
    return (row << 6) + ((((kelem >> 3) ^ SW2(row))) << 4) + ((kelem & 7) << 1);
}
__device__ __forceinline__ f32x4 mfma16(bf16x8 a, bf16x8 b, f32x4 c) {
    return __builtin_amdgcn_mfma_f32_16x16x32_bf16(a, b, c, 0, 0, 0);
}
__device__ __forceinline__ void gload_lds16(const void* g, void* lds) {
    __builtin_amdgcn_global_load_lds(
        (const __attribute__((address_space(1))) unsigned*)g,
        (__attribute__((address_space(3))) unsigned*)lds, 16, 0, 0);
}

// ---------------- x fp32 -> bf16 ----------------
__global__ __launch_bounds__(256) void k_cvt(const float* __restrict__ x,
                                             unsigned short* __restrict__ xbf) {
    int i = blockIdx.x * 256 + threadIdx.x;
    float4 v = ((const float4*)x)[i];
    uint2 p{pack2f(v.x, v.y), pack2f(v.z, v.w)};
    ((uint2*)xbf)[i] = p;
}

// ---------------- Router ----------------
__global__ void k_router(const float* __restrict__ x, const float* __restrict__ Wr,
                         const float* __restrict__ bias, float* __restrict__ wtok,
                         int* __restrict__ idxtok, int* __restrict__ counts) {
    int t = blockIdx.x;
    int lane = threadIdx.x & 63;
    int wave = threadIdx.x >> 6;
    __shared__ float lg[NE];
    const float4* xr = (const float4*)(x + (size_t)t * HDIM);
    for (int e = wave; e < NE; e += 4) {
        const float4* wr = (const float4*)(Wr + (size_t)e * HDIM);
        float s = 0.f;
        for (int j = lane; j < HDIM / 4; j += 64) {
            float4 a = xr[j], b = wr[j];
            s += a.x*b.x + a.y*b.y + a.z*b.z + a.w*b.w;
        }
        #pragma unroll
        for (int d = 32; d; d >>= 1) s += __shfl_xor(s, d);
        if (lane == 0) lg[e] = s + bias[e];
    }
    __syncthreads();
    if (threadIdx.x == 0) {
        float m = lg[0];
        #pragma unroll
        for (int e = 1; e < NE; e++) m = fmaxf(m, lg[e]);
        float p[NE]; float S = 0.f;
        #pragma unroll
        for (int e = 0; e < NE; e++) { p[e] = expf(lg[e] - m); S += p[e]; }
        int i0 = 0;
        #pragma unroll
        for (int e = 1; e < NE; e++) if (p[e] > p[i0]) i0 = e;
        int i1 = (i0 == 0) ? 1 : 0;
        for (int e = 0; e < NE; e++) if (e != i0 && p[e] > p[i1]) i1 = e;
        float v0 = p[i0] / S, v1 = p[i1] / S;
        float wsum = v0 + v1 + 1e-9f;
        wtok[t*2+0] = v0 / wsum;
        wtok[t*2+1] = v1 / wsum;
        idxtok[t*2+0] = i0;
        idxtok[t*2+1] = i1;
        atomicAdd(&counts[i0], 1);
        atomicAdd(&counts[i1], 1);
    }
}

// ---------------- scan + tile work-list ----------------
__global__ void k_scan(const int* __restrict__ counts, int* __restrict__ offs,
                       int* __restrict__ cursor, int4* __restrict__ tiles) {
    if (threadIdx.x == 0) {
        int acc = 0;
        for (int e = 0; e < NEX; e++) {
            offs[e] = acc; cursor[e] = acc;
            acc += (e < NE) ? counts[e] : T_TOK;
        }
        offs[NEX] = acc;
        int nt = 0;
        for (int e = 0; e < NEX; e++) {
            for (int r = offs[e]; r < offs[e+1]; r += 128) {
                tiles[nt] = int4{r, min(128, offs[e+1] - r), e, 0};
                nt++;
            }
        }
        for (; nt < TM; nt++) tiles[nt] = int4{0, 0, 0, 0};
    }
}

__global__ void k_scatter(const int* __restrict__ idxtok, const float* __restrict__ wtok,
                          int* __restrict__ cursor, const int* __restrict__ offs,
                          int* __restrict__ rows, float* __restrict__ wrow) {
    int t = blockIdx.x * blockDim.x + threadIdx.x;
    if (t >= T_TOK) return;
    #pragma unroll
    for (int k = 0; k < 2; k++) {
        int e = idxtok[t*2+k];
        int pos = atomicAdd(&cursor[e], 1);
        rows[pos] = t;
        wrow[pos] = wtok[t*2+k];
    }
    int p16 = offs[NE] + t;
    rows[p16] = t;
    wrow[p16] = 1.0f;
}

// ---------------- GEMM1: act = w * silu(X@Wg) * (X@Wu) -> bf16 ----------------
// tile 128x64, BK=32, NK=64, 512 thr (8 waves 2x4). LDS 32KB.
// A via gload_lds DMA (pre-swizzled src, dbuf). W: 8 coalesced dwords/thread ->
// one conflict-free ds_write_b128 per thread. Raw barrier + exact vmcnt ledger:
// per step queue = [Wcur{8}, A{1}, Wnext{8}]; vmcnt(9) frees Wcur, vmcnt(8)
// frees A before barrier, Wnext{8} stays in flight a full step.
__global__ __launch_bounds__(512) void k_gemm1(
        const unsigned short* __restrict__ xbf,
        const float* __restrict__ Wg, const float* __restrict__ Wu,
        const float* __restrict__ sWg, const float* __restrict__ sWu,
        const int4* __restrict__ tiles, const int* __restrict__ rows,
        const float* __restrict__ wrow, unsigned short* __restrict__ act) {
    int bid = blockIdx.x;
    int wg = (bid & 7) * (G1_NWG >> 3) + (bid >> 3);   // XCD-chunked
    int ti = wg & (TM - 1);
    int ct = wg >> 6;

    int4 tl = tiles[ti];
    int nrows = tl.y;
    if (nrows == 0) return;
    int rs = tl.x, e = tl.z;
    const float* wgp = (e < NE) ? Wg + (size_t)e * HDIM * IDIM : sWg;
    const float* wup = (e < NE) ? Wu + (size_t)e * HDIM * IDIM : sWu;
    int n0 = ct * 64;

    __shared__ unsigned short As[2][128 * 32];   // 16 KB
    __shared__ unsigned short Bs[2][64 * 32];    // 8 KB
    __shared__ unsigned short Us[2][64 * 32];    // 8 KB

    int tid = threadIdx.x;
    int l = tid & 63, w = tid >> 6;

    // A DMA: wave w covers rows w*16..w*16+15; lane: row = w*16+(l>>2), chunk l&3,
    // source chunk pre-swizzled so linear DMA dest matches swizzled reads.
    int arow = w * 16 + (l >> 2);
    int rr = rows[rs + min(arow, nrows - 1)];
    const unsigned short* asrc = xbf + (size_t)rr * HDIM + (((l & 3) ^ SW2(arow)) << 3);

    // W staging: thread = (matrix sm, col sn, k-chunk skc of 8). 8 coalesced
    // dword loads (lanes span 64 consecutive n) -> 1 ds_write_b128 (conflict-free).
    int sm = tid >> 8;               // 0: Wg->Bs, 1: Wu->Us
    int sn = tid & 63;
    int skc = (tid >> 6) & 3;
    const float* wsrc = (sm ? wup : wgp) + (size_t)(skc * 8) * IDIM + n0 + sn;
    unsigned short* wdst0 = sm ? Us[0] : Bs[0];
    unsigned short* wdst1 = sm ? Us[1] : Bs[1];
    int swoff = lds_off32(sn, skc * 8);

    int wr = (w >> 2) << 6;      // 0/64
    int wc = (w & 3) << 4;       // 0/16/32/48
    int fr = l & 15;
    int fk = (l >> 4) << 3;

    float wA[8], wB[8];
    f32x4 accg[4] = {}, accu[4] = {};
    const int NK = HDIM / 32;    // 64

    #define G1_LOADW(DST, KS) do { \
        size_t kb_ = (size_t)(KS) * 32; \
        _Pragma("unroll") \
        for (int j = 0; j < 8; ++j) DST[j] = wsrc[(kb_ + j) * IDIM]; \
    } while (0)
    #define G1_WRITEW(SRC, P) do { \
        uint4 pw_; \
        pw_.x = pack2f(SRC[0], SRC[1]); pw_.y = pack2f(SRC[2], SRC[3]); \
        pw_.z = pack2f(SRC[4], SRC[5]); pw_.w = pack2f(SRC[6], SRC[7]); \
        *(uint4*)((char*)((P) ? wdst1 : wdst0) + swoff) = pw_; \
    } while (0)
    #define G1_MFMA(P) do { \
        bf16x8 a0 = *(const bf16x8*)((const char*)As[P] + lds_off32(wr + fr, fk)); \
        bf16x8 a1 = *(const bf16x8*)((const char*)As[P] + lds_off32(wr + 16 + fr, fk)); \
        bf16x8 a2 = *(const bf16x8*)((const char*)As[P] + lds_off32(wr + 32 + fr, fk)); \
        bf16x8 a3 = *(const bf16x8*)((const char*)As[P] + lds_off32(wr + 48 + fr, fk)); \
        bf16x8 bg = *(const bf16x8*)((const char*)Bs[P] + lds_off32(wc + fr, fk)); \
        bf16x8 bu = *(const bf16x8*)((const char*)Us[P] + lds_off32(wc + fr, fk)); \
        accg[0] = mfma16(a0, bg, accg[0]);  accu[0] = mfma16(a0, bu, accu[0]); \
        accg[1] = mfma16(a1, bg, accg[1]);  accu[1] = mfma16(a1, bu, accu[1]); \
        accg[2] = mfma16(a2, bg, accg[2]);  accu[2] = mfma16(a2, bu, accu[2]); \
        accg[3] = mfma16(a3, bg, accg[3]);  accu[3] = mfma16(a3, bu, accu[3]); \
    } while (0)
    // step K (parity P = K&1 as literal): MFMA reads As[P],Ws[P];
    // DMA A(K+1)->As[P^1]; write W(K+1) regs (CUR) -> Ws[P^1]; load W(K+2)->NXT.
    #define G1_STEP(K, CUR, NXT, P) do { \
        gload_lds16(asrc + min((K) + 1, NK - 1) * 32, (char*)As[(P) ^ 1] + w * 1024); \
        SCHEDB; \
        G1_LOADW(NXT, min((K) + 2, NK - 1)); \
        SCHEDB; \
        WAITVM(9);              /* retire CUR regs; leave A{1}+NXT{8} */ \
        G1_WRITEW(CUR, (P) ^ 1); \
        G1_MFMA(P); \
        SCHEDB; \
        WAITVM(8);              /* retire A-DMA; leave NXT{8} */ \
        WAITLGKM0; \
        BARRIER; \
        SCHEDB; \
    } while (0)

    // prologue: queue ledger -> [wB = W(1){8}] at loop entry
    G1_LOADW(wA, 0);                                   // W(0) [8]
    gload_lds16(asrc, (char*)As[0] + w * 1024);        // A(0) [1] -> 9
    SCHEDB;
    G1_LOADW(wB, 1);                                   // W(1) [8] -> 17
    SCHEDB;
    WAITVM(9);                                         // retire W(0)
    G1_WRITEW(wA, 0);                                  // stage W(0) -> buf0
    SCHEDB;
    WAITVM(8);                                         // retire A(0); leave W(1)
    WAITLGKM0;
    BARRIER;
    SCHEDB;

    for (int k = 0; k < NK; k += 2) {
        G1_STEP(k,     wB, wA, 0);
        G1_STEP(k + 1, wA, wB, 1);
    }
    asm volatile("s_waitcnt vmcnt(0)" ::: "memory");

    int crow = (l >> 4) << 2;
    int ccol = l & 15;
    #pragma unroll
    for (int m = 0; m < 4; ++m) {
        #pragma unroll
        for (int reg = 0; reg < 4; ++reg) {
            int r = wr + m * 16 + crow + reg;
            if (r < nrows) {
                float wv = wrow[rs + r];
                float g = accg[m][reg], u = accu[m][reg];
                act[(size_t)(rs + r) * IDIM + n0 + wc + ccol] =
                    f2bf(g / (1.f + __expf(-g)) * u * wv);
            }
        }
    }
    #undef G1_LOADW
    #undef G1_WRITEW
    #undef G1_MFMA
    #undef G1_STEP
}

// ---------------- GEMM2: out[tok] += act @ Wd ----------------
// tile 128x64, BK=32, NK=32, 512 thr. LDS 24KB. Same ledger with W{4}/thread:
// vmcnt(5) frees Wcur, vmcnt(4) frees A.
__global__ __launch_bounds__(512) void k_gemm2(
        const unsigned short* __restrict__ act,
        const float* __restrict__ Wd, const float* __restrict__ sWd,
        const int4* __restrict__ tiles, const int* __restrict__ rows,
        float* __restrict__ out) {
    int bid = blockIdx.x;
    int wg = (bid & 7) * (G2_NWG >> 3) + (bid >> 3);
    int ti = wg & (TM - 1);
    int ct = wg >> 6;

    int4 tl = tiles[ti];
    int nrows = tl.y;
    if (nrows == 0) return;
    int rs = tl.x, e = tl.z;
    const float* wdp = (e < NE) ? Wd + (size_t)e * IDIM * HDIM : sWd;
    int n0 = ct * 64;

    __shared__ unsigned short As[2][128 * 32];   // 16 KB
    __shared__ unsigned short Bs[2][64 * 32];    // 8 KB

    int tid = threadIdx.x;
    int l = tid & 63, w = tid >> 6;

    int arow = w * 16 + (l >> 2);
    const unsigned short* asrc =
        act + (size_t)(rs + min(arow, nrows - 1)) * IDIM + (((l & 3) ^ SW2(arow)) << 3);

    // W staging: thread = (col sn, k-chunk skc of 4); 4 coalesced dwords ->
    // one ds_write_b64 (2-way max = free).
    int sn = tid & 63;
    int skc = (tid >> 6) & 7;
    const float* wsrc = wdp + (size_t)(skc * 4) * HDIM + n0 + sn;
    int swoff = lds_off32(sn, skc * 4);

    int wr = (w >> 2) << 6;
    int wc = (w & 3) << 4;
    int fr = l & 15;
    int fk = (l >> 4) << 3;

    float wA[4], wB[4];
    f32x4 acc[4] = {};
    const int NK = IDIM / 32;    // 32

    #define G2_LOADW(DST, KS) do { \
        size_t kb_ = (size_t)(KS) * 32; \
        _Pragma("unroll") \
        for (int j = 0; j < 4; ++j) DST[j] = wsrc[(kb_ + j) * HDIM]; \
    } while (0)
    #define G2_WRITEW(SRC, P) do { \
        uint2 pw_; \
        pw_.x = pack2f(SRC[0], SRC[1]); pw_.y = pack2f(SRC[2], SRC[3]); \
        *(uint2*)((char*)Bs[P] + swoff) = pw_; \
    } while (0)
    #define G2_MFMA(P) do { \
        bf16x8 a0 = *(const bf16x8*)((const char*)As[P] + lds_off32(wr + fr, fk)); \
        bf16x8 a1 = *(const bf16x8*)((const char*)As[P] + lds_off32(wr + 16 + fr, fk)); \
        bf16x8 a2 = *(const bf16x8*)((const char*)As[P] + lds_off32(wr + 32 + fr, fk)); \
        bf16x8 a3 = *(const bf16x8*)((const char*)As[P] + lds_off32(wr + 48 + fr, fk)); \
        bf16x8 b  = *(const bf16x8*)((const char*)Bs[P] + lds_off32(wc + fr, fk)); \
        acc[0] = mfma16(a0, b, acc[0]); \
        acc[1] = mfma16(a1, b, acc[1]); \
        acc[2] = mfma16(a2, b, acc[2]); \
        acc[3] = mfma16(a3, b, acc[3]); \
    } while (0)
    #define G2_STEP(K, CUR, NXT, P) do { \
        gload_lds16(asrc + min((K) + 1, NK - 1) * 32, (char*)As[(P) ^ 1] + w * 1024); \
        SCHEDB; \
        G2_LOADW(NXT, min((K) + 2, NK - 1)); \
        SCHEDB; \
        WAITVM(5); \
        G2_WRITEW(CUR, (P) ^ 1); \
        G2_MFMA(P); \
        SCHEDB; \
        WAITVM(4); \
        WAITLGKM0; \
        BARRIER; \
        SCHEDB; \
    } while (0)

    G2_LOADW(wA, 0);                                   // [4]
    gload_lds16(asrc, (char*)As[0] + w * 1024);        // [1] -> 5
    SCHEDB;
    G2_LOADW(wB, 1);                                   // [4] -> 9
    SCHEDB;
    WAITVM(5);                                         // retire W(0)
    G2_WRITEW(wA, 0);
    SCHEDB;
    WAITVM(4);                                         // retire A(0); leave W(1)
    WAITLGKM0;
    BARRIER;
    SCHEDB;

    for (int k = 0; k < NK; k += 2) {
        G2_STEP(k,     wB, wA, 0);
        G2_STEP(k + 1, wA, wB, 1);
    }
    asm volatile("s_waitcnt vmcnt(0)" ::: "memory");

    int crow = (l >> 4) << 2;
    int ccol = l & 15;
    #pragma unroll
    for (int m = 0; m < 4; ++m) {
        #pragma unroll
        for (int reg = 0; reg < 4; ++reg) {
            int r = wr + m * 16 + crow + reg;
            if (r < nrows) {
                atomicAdd(&out[(size_t)rows[rs + r] * HDIM + n0 + wc + ccol], acc[m][reg]);
            }
        }
    }
    #undef G2_LOADW
    #undef G2_WRITEW
    #undef G2_MFMA
    #undef G2_STEP
}

extern "C" void kernel_launch(void* const* d_in, const int* in_sizes, int n_in,
                              void* d_out, int out_size, void* d_ws, size_t ws_size,
                              hipStream_t stream) {
    const float* x    = (const float*)d_in[0];
    const float* Wr   = (const float*)d_in[1];
    const float* bias = (const float*)d_in[2];
    const float* Wg   = (const float*)d_in[3];
    const float* Wu   = (const float*)d_in[4];
    const float* Wd   = (const float*)d_in[5];
    const float* sWg  = (const float*)d_in[6];
    const float* sWu  = (const float*)d_in[7];
    const float* sWd  = (const float*)d_in[8];
    float* out = (float*)d_out;

    char* p = (char*)d_ws;
    int*   counts = (int*)p;                 p += 256;
    int*   offs   = (int*)p;                 p += 256;
    int*   cursor = (int*)p;                 p += 256;
    int4*  tiles  = (int4*)p;                p += TM * sizeof(int4);
    int*   idxtok = (int*)p;                 p += (size_t)T_TOK * 2 * sizeof(int);
    float* wtok   = (float*)p;               p += (size_t)T_TOK * 2 * sizeof(float);
    int*   rows   = (int*)p;                 p += (size_t)NASSIGN * sizeof(int);
    float* wrow   = (float*)p;               p += (size_t)NASSIGN * sizeof(float);
    unsigned short* act = (unsigned short*)p; p += (size_t)NASSIGN * IDIM * sizeof(unsigned short);
    unsigned short* xbf = (unsigned short*)p; // 8.4MB

    hipMemsetAsync(counts, 0, 256, stream);
    hipMemsetAsync(d_out, 0, (size_t)out_size * sizeof(float), stream);

    k_cvt<<<dim3(T_TOK * HDIM / 1024), dim3(256), 0, stream>>>(x, xbf);
    k_router<<<dim3(T_TOK), dim3(256), 0, stream>>>(x, Wr, bias, wtok, idxtok, counts);
    k_scan<<<dim3(1), dim3(64), 0, stream>>>(counts, offs, cursor, tiles);
    k_scatter<<<dim3((T_TOK + 255) / 256), dim3(256), 0, stream>>>(idxtok, wtok, cursor, offs, rows, wrow);
    k_gemm1<<<dim3(G1_NWG), dim3(512), 0, stream>>>(xbf, Wg, Wu, sWg, sWu, tiles, rows, wrow, act);
    k_gemm2<<<dim3(G2_NWG), dim3(512), 0, stream>>>(act, Wd, sWd, tiles, rows, out);
}

// Round 15
// 349.012 us; speedup vs baseline: 1.2589x; 1.0133x over previous
//
#include <hip/hip_runtime.h>
#include <hip/hip_bf16.h>

#define T_TOK 2048
#define HDIM  2048
#define IDIM  1024
#define NE    16
#define NEX   17
#define NASSIGN (T_TOK*3)
#define TM    64                    // 128-row tiles: max 47 routed + 16 shared

#define G1_NWG (TM*16)              // 1024
#define G2_NWG (TM*32)              // 2048

typedef __attribute__((ext_vector_type(8))) short bf16x8;
typedef __attribute__((ext_vector_type(4))) float f32x4;

#define WAITVM(N) asm volatile("s_waitcnt vmcnt(" #N ")" ::: "memory")
#define WAITLGKM0 asm volatile("s_waitcnt lgkmcnt(0)" ::: "memory")
#define SCHEDB    __builtin_amdgcn_sched_barrier(0)
#define BARRIER   __builtin_amdgcn_s_barrier()

__device__ __forceinline__ unsigned short f2bf(float f) {
    union { float f; unsigned u; } v; v.f = f;
    unsigned r = v.u + 0x7fffu + ((v.u >> 16) & 1u);
    return (unsigned short)(r >> 16);
}
__device__ __forceinline__ unsigned pack2f(float a, float b) {
    __hip_bfloat162 h = __float22bfloat162_rn(float2{a, b});
    unsigned r;
    __builtin_memcpy(&r, &h, 4);
    return r;
}
// swizzle for 64B LDS rows (32 bf16): 4 chunks of 16B, slot = (k>>3) ^ ((row>>1)&3)
__device__ __forceinline__ int SW2(int r) { return (r >> 1) & 3; }
__device__ __forceinline__ int lds_off32(int row, int kelem) {
    return (row << 6) + ((((kelem >> 3) ^ SW2(row))) << 4) + ((kelem & 7) << 1);
}
__device__ __forceinline__ f32x4 mfma16(bf16x8 a, bf16x8 b, f32x4 c) {
    return __builtin_amdgcn_mfma_f32_16x16x32_bf16(a, b, c, 0, 0, 0);
}
__device__ __forceinline__ void gload_lds16(const void* g, void* lds) {
    __builtin_amdgcn_global_load_lds(
        (const __attribute__((address_space(1))) unsigned*)g,
        (__attribute__((address_space(3))) unsigned*)lds, 16, 0, 0);
}

// ---------------- x fp32 -> bf16 ----------------
__global__ __launch_bounds__(256) void k_cvt(const float* __restrict__ x,
                                             unsigned short* __restrict__ xbf) {
    int i = blockIdx.x * 256 + threadIdx.x;
    float4 v = ((const float4*)x)[i];
    uint2 p{pack2f(v.x, v.y), pack2f(v.z, v.w)};
    ((uint2*)xbf)[i] = p;
}

// ---------------- Router ----------------
__global__ void k_router(const float* __restrict__ x, const float* __restrict__ Wr,
                         const float* __restrict__ bias, float* __restrict__ wtok,
                         int* __restrict__ idxtok, int* __restrict__ counts) {
    int t = blockIdx.x;
    int lane = threadIdx.x & 63;
    int wave = threadIdx.x >> 6;
    __shared__ float lg[NE];
    const float4* xr = (const float4*)(x + (size_t)t * HDIM);
    for (int e = wave; e < NE; e += 4) {
        const float4* wr = (const float4*)(Wr + (size_t)e * HDIM);
        float s = 0.f;
        for (int j = lane; j < HDIM / 4; j += 64) {
            float4 a = xr[j], b = wr[j];
            s += a.x*b.x + a.y*b.y + a.z*b.z + a.w*b.w;
        }
        #pragma unroll
        for (int d = 32; d; d >>= 1) s += __shfl_xor(s, d);
        if (lane == 0) lg[e] = s + bias[e];
    }
    __syncthreads();
    if (threadIdx.x == 0) {
        float m = lg[0];
        #pragma unroll
        for (int e = 1; e < NE; e++) m = fmaxf(m, lg[e]);
        float p[NE]; float S = 0.f;
        #pragma unroll
        for (int e = 0; e < NE; e++) { p[e] = expf(lg[e] - m); S += p[e]; }
        int i0 = 0;
        #pragma unroll
        for (int e = 1; e < NE; e++) if (p[e] > p[i0]) i0 = e;
        int i1 = (i0 == 0) ? 1 : 0;
        for (int e = 0; e < NE; e++) if (e != i0 && p[e] > p[i1]) i1 = e;
        float v0 = p[i0] / S, v1 = p[i1] / S;
        float wsum = v0 + v1 + 1e-9f;
        wtok[t*2+0] = v0 / wsum;
        wtok[t*2+1] = v1 / wsum;
        idxtok[t*2+0] = i0;
        idxtok[t*2+1] = i1;
        atomicAdd(&counts[i0], 1);
        atomicAdd(&counts[i1], 1);
    }
}

// ---------------- scan + tile work-list ----------------
__global__ void k_scan(const int* __restrict__ counts, int* __restrict__ offs,
                       int* __restrict__ cursor, int4* __restrict__ tiles) {
    if (threadIdx.x == 0) {
        int acc = 0;
        for (int e = 0; e < NEX; e++) {
            offs[e] = acc; cursor[e] = acc;
            acc += (e < NE) ? counts[e] : T_TOK;
        }
        offs[NEX] = acc;
        int nt = 0;
        for (int e = 0; e < NEX; e++) {
            for (int r = offs[e]; r < offs[e+1]; r += 128) {
                tiles[nt] = int4{r, min(128, offs[e+1] - r), e, 0};
                nt++;
            }
        }
        for (; nt < TM; nt++) tiles[nt] = int4{0, 0, 0, 0};
    }
}

__global__ void k_scatter(const int* __restrict__ idxtok, const float* __restrict__ wtok,
                          int* __restrict__ cursor, const int* __restrict__ offs,
                          int* __restrict__ rows, float* __restrict__ wrow) {
    int t = blockIdx.x * blockDim.x + threadIdx.x;
    if (t >= T_TOK) return;
    #pragma unroll
    for (int k = 0; k < 2; k++) {
        int e = idxtok[t*2+k];
        int pos = atomicAdd(&cursor[e], 1);
        rows[pos] = t;
        wrow[pos] = wtok[t*2+k];
    }
    int p16 = offs[NE] + t;
    rows[p16] = t;
    wrow[p16] = 1.0f;
}

// ---------------- GEMM1: act = w * silu(X@Wg) * (X@Wu) -> bf16 ----------------
// tile 128x64, BK=64 (two 32-k subtiles), NK=32 steps, 512 thr (8 waves 2x4).
// LDS 48KB -> 3 blocks/CU. A dbuf via gload_lds DMA (r14-proven pre-swizzle);
// W single-buffered, reg-staged, conflict-free b128 writes (r14-proven layout).
// Counted vmcnt: [A(k+1){2}, W(k+2){16}] fly across each MFMA phase.
__global__ __launch_bounds__(512) void k_gemm1(
        const unsigned short* __restrict__ xbf,
        const float* __restrict__ Wg, const float* __restrict__ Wu,
        const float* __restrict__ sWg, const float* __restrict__ sWu,
        const int4* __restrict__ tiles, const int* __restrict__ rows,
        const float* __restrict__ wrow, unsigned short* __restrict__ act) {
    int bid = blockIdx.x;
    int wg = (bid & 7) * (G1_NWG >> 3) + (bid >> 3);   // XCD-chunked
    int ti = wg & (TM - 1);
    int ct = wg >> 6;

    int4 tl = tiles[ti];
    int nrows = tl.y;
    if (nrows == 0) return;
    int rs = tl.x, e = tl.z;
    const float* wgp = (e < NE) ? Wg + (size_t)e * HDIM * IDIM : sWg;
    const float* wup = (e < NE) ? Wu + (size_t)e * HDIM * IDIM : sWu;
    int n0 = ct * 64;

    __shared__ unsigned short As[2][8192];   // [buf][2 halves x 128x32] 32KB
    __shared__ unsigned short Bs[4096];      // [2 halves x 64x32] 8KB, single-buf
    __shared__ unsigned short Us[4096];      // 8KB

    int tid = threadIdx.x;
    int l = tid & 63, w = tid >> 6;

    // A DMA: wave w stages rows w*16..w*16+15 of each 32-k half; lane row =
    // w*16+(l>>2), chunk (l&3), source chunk pre-swizzled (r14-proven).
    int arow = w * 16 + (l >> 2);
    int rr = rows[rs + min(arow, nrows - 1)];
    const unsigned short* asrc = xbf + (size_t)rr * HDIM + (((l & 3) ^ SW2(arow)) << 3);

    // W staging: thread = (matrix sm, col sn, chunk skc). Per step: 2 halves x
    // 8 coalesced dwords -> 2 conflict-free ds_write_b128.
    int sm = tid >> 8;               // 0: Wg->Bs, 1: Wu->Us
    int sn = tid & 63;
    int skc = (tid >> 6) & 3;
    const float* wsrc = (sm ? wup : wgp) + (size_t)(skc * 8) * IDIM + n0 + sn;
    char* wdst = (char*)(sm ? Us : Bs);
    int swoff = lds_off32(sn, skc * 8);

    int wr = (w >> 2) << 6;      // 0/64
    int wc = (w & 3) << 4;       // 0/16/32/48
    int fr = l & 15;
    int fk = (l >> 4) << 3;

    float wA[16], wB[16];
    f32x4 accg[4] = {}, accu[4] = {};
    const int NK = HDIM / 64;    // 32

    #define G1_LOADW(DST, KS) do { \
        size_t kb_ = (size_t)(KS) * 64; \
        _Pragma("unroll") \
        for (int h = 0; h < 2; ++h) { \
            _Pragma("unroll") \
            for (int j = 0; j < 8; ++j) \
                DST[h * 8 + j] = wsrc[(kb_ + h * 32 + j) * IDIM]; \
        } \
    } while (0)
    #define G1_WRITEW(SRC) do { \
        _Pragma("unroll") \
        for (int h = 0; h < 2; ++h) { \
            uint4 pw_; \
            pw_.x = pack2f(SRC[h*8+0], SRC[h*8+1]); pw_.y = pack2f(SRC[h*8+2], SRC[h*8+3]); \
            pw_.z = pack2f(SRC[h*8+4], SRC[h*8+5]); pw_.w = pack2f(SRC[h*8+6], SRC[h*8+7]); \
            *(uint4*)(wdst + h * 4096 + swoff) = pw_; \
        } \
    } while (0)
    #define G1_DMA(KS, P) do { \
        gload_lds16(asrc + (size_t)(KS) * 64,      (char*)As[P] + w * 1024); \
        gload_lds16(asrc + (size_t)(KS) * 64 + 32, (char*)As[P] + 8192 + w * 1024); \
    } while (0)
    #define G1_MFMA(P) do { \
        _Pragma("unroll") \
        for (int kh = 0; kh < 2; ++kh) { \
            const char* Ab = (const char*)As[P] + kh * 8192; \
            const char* Bb = (const char*)Bs + kh * 4096; \
            const char* Ub = (const char*)Us + kh * 4096; \
            bf16x8 a0 = *(const bf16x8*)(Ab + lds_off32(wr + fr, fk)); \
            bf16x8 a1 = *(const bf16x8*)(Ab + lds_off32(wr + 16 + fr, fk)); \
            bf16x8 a2 = *(const bf16x8*)(Ab + lds_off32(wr + 32 + fr, fk)); \
            bf16x8 a3 = *(const bf16x8*)(Ab + lds_off32(wr + 48 + fr, fk)); \
            bf16x8 bg = *(const bf16x8*)(Bb + lds_off32(wc + fr, fk)); \
            bf16x8 bu = *(const bf16x8*)(Ub + lds_off32(wc + fr, fk)); \
            accg[0] = mfma16(a0, bg, accg[0]);  accu[0] = mfma16(a0, bu, accu[0]); \
            accg[1] = mfma16(a1, bg, accg[1]);  accu[1] = mfma16(a1, bu, accu[1]); \
            accg[2] = mfma16(a2, bg, accg[2]);  accu[2] = mfma16(a2, bu, accu[2]); \
            accg[3] = mfma16(a3, bg, accg[3]);  accu[3] = mfma16(a3, bu, accu[3]); \
        } \
    } while (0)
    // step K: entry in-flight [A(K+1){2}, W(K+2){16}]; CUR = W(K+1) (retired).
    #define G1_STEP(K, CUR, P) do { \
        G1_MFMA(P); \
        SCHEDB; \
        BARRIER; \
        SCHEDB; \
        G1_DMA(min((K) + 2, NK - 1), P); \
        G1_WRITEW(CUR); \
        SCHEDB; \
        WAITVM(2);            /* retire A(K+1)+W(K+2); leave A(K+2){2} */ \
        G1_LOADW(CUR, min((K) + 3, NK - 1)); \
        SCHEDB; \
        WAITLGKM0; \
        BARRIER; \
        SCHEDB; \
    } while (0)

    // prologue: establish invariant for k=0
    G1_LOADW(wA, 0);         // [W0{16}]
    G1_DMA(0, 0);            // [W0, A0{2}] = 18
    G1_LOADW(wB, 1);         // [W0, A0, W1{16}] = 34
    SCHEDB;
    WAITVM(18);              // retire W0 -> wA valid
    G1_WRITEW(wA);           // stage W0
    G1_DMA(1, 1);            // [A0, W1, A1{2}] = 20
    SCHEDB;
    WAITVM(2);               // retire A0+W1 -> wB valid; [A1{2}]
    G1_LOADW(wA, 2);         // [A1{2}, W2{16}] = 18  (invariant)
    SCHEDB;
    WAITLGKM0;
    BARRIER;
    SCHEDB;

    for (int k = 0; k < NK; k += 2) {
        G1_STEP(k,     wB, 0);
        G1_STEP(k + 1, wA, 1);
    }
    WAITVM(0);

    int crow = (l >> 4) << 2;
    int ccol = l & 15;
    #pragma unroll
    for (int m = 0; m < 4; ++m) {
        #pragma unroll
        for (int reg = 0; reg < 4; ++reg) {
            int r = wr + m * 16 + crow + reg;
            if (r < nrows) {
                float wv = wrow[rs + r];
                float g = accg[m][reg], u = accu[m][reg];
                act[(size_t)(rs + r) * IDIM + n0 + wc + ccol] =
                    f2bf(g / (1.f + __expf(-g)) * u * wv);
            }
        }
    }
    #undef G1_LOADW
    #undef G1_WRITEW
    #undef G1_DMA
    #undef G1_MFMA
    #undef G1_STEP
}

// ---------------- GEMM2: out[tok] += act @ Wd ----------------
// tile 128x64, BK=64, NK=16 steps, 512 thr. LDS 40KB -> 4 blocks/CU.
__global__ __launch_bounds__(512) void k_gemm2(
        const unsigned short* __restrict__ act,
        const float* __restrict__ Wd, const float* __restrict__ sWd,
        const int4* __restrict__ tiles, const int* __restrict__ rows,
        float* __restrict__ out) {
    int bid = blockIdx.x;
    int wg = (bid & 7) * (G2_NWG >> 3) + (bid >> 3);
    int ti = wg & (TM - 1);
    int ct = wg >> 6;

    int4 tl = tiles[ti];
    int nrows = tl.y;
    if (nrows == 0) return;
    int rs = tl.x, e = tl.z;
    const float* wdp = (e < NE) ? Wd + (size_t)e * IDIM * HDIM : sWd;
    int n0 = ct * 64;

    __shared__ unsigned short As[2][8192];   // 32KB
    __shared__ unsigned short Bs[4096];      // 8KB single-buf (2 halves)

    int tid = threadIdx.x;
    int l = tid & 63, w = tid >> 6;

    int arow = w * 16 + (l >> 2);
    const unsigned short* asrc =
        act + (size_t)(rs + min(arow, nrows - 1)) * IDIM + (((l & 3) ^ SW2(arow)) << 3);

    // W staging: thread = (col sn, chunk skc of 8); 8 coalesced dwords ->
    // one conflict-free ds_write_b128 into half skc>>2.
    int sn = tid & 63;
    int skc = (tid >> 6) & 7;
    const float* wsrc = wdp + (size_t)(skc * 8) * HDIM + n0 + sn;
    int swoff = ((skc >> 2) * 4096) + lds_off32(sn, (skc & 3) * 8);

    int wr = (w >> 2) << 6;
    int wc = (w & 3) << 4;
    int fr = l & 15;
    int fk = (l >> 4) << 3;

    float wA[8], wB[8];
    f32x4 acc[4] = {};
    const int NK = IDIM / 64;    // 16

    #define G2_LOADW(DST, KS) do { \
        size_t kb_ = (size_t)(KS) * 64; \
        _Pragma("unroll") \
        for (int j = 0; j < 8; ++j) DST[j] = wsrc[(kb_ + j) * HDIM]; \
    } while (0)
    #define G2_WRITEW(SRC) do { \
        uint4 pw_; \
        pw_.x = pack2f(SRC[0], SRC[1]); pw_.y = pack2f(SRC[2], SRC[3]); \
        pw_.z = pack2f(SRC[4], SRC[5]); pw_.w = pack2f(SRC[6], SRC[7]); \
        *(uint4*)((char*)Bs + swoff) = pw_; \
    } while (0)
    #define G2_DMA(KS, P) do { \
        gload_lds16(asrc + (size_t)(KS) * 64,      (char*)As[P] + w * 1024); \
        gload_lds16(asrc + (size_t)(KS) * 64 + 32, (char*)As[P] + 8192 + w * 1024); \
    } while (0)
    #define G2_MFMA(P) do { \
        _Pragma("unroll") \
        for (int kh = 0; kh < 2; ++kh) { \
            const char* Ab = (const char*)As[P] + kh * 8192; \
            const char* Bb = (const char*)Bs + kh * 4096; \
            bf16x8 a0 = *(const bf16x8*)(Ab + lds_off32(wr + fr, fk)); \
            bf16x8 a1 = *(const bf16x8*)(Ab + lds_off32(wr + 16 + fr, fk)); \
            bf16x8 a2 = *(const bf16x8*)(Ab + lds_off32(wr + 32 + fr, fk)); \
            bf16x8 a3 = *(const bf16x8*)(Ab + lds_off32(wr + 48 + fr, fk)); \
            bf16x8 b  = *(const bf16x8*)(Bb + lds_off32(wc + fr, fk)); \
            acc[0] = mfma16(a0, b, acc[0]); \
            acc[1] = mfma16(a1, b, acc[1]); \
            acc[2] = mfma16(a2, b, acc[2]); \
            acc[3] = mfma16(a3, b, acc[3]); \
        } \
    } while (0)
    #define G2_STEP(K, CUR, P) do { \
        G2_MFMA(P); \
        SCHEDB; \
        BARRIER; \
        SCHEDB; \
        G2_DMA(min((K) + 2, NK - 1), P); \
        G2_WRITEW(CUR); \
        SCHEDB; \
        WAITVM(2); \
        G2_LOADW(CUR, min((K) + 3, NK - 1)); \
        SCHEDB; \
        WAITLGKM0; \
        BARRIER; \
        SCHEDB; \
    } while (0)

    G2_LOADW(wA, 0);         // [W0{8}]
    G2_DMA(0, 0);            // [W0, A0{2}] = 10
    G2_LOADW(wB, 1);         // [W0, A0, W1{8}] = 18
    SCHEDB;
    WAITVM(10);              // retire W0 -> wA
    G2_WRITEW(wA);
    G2_DMA(1, 1);            // [A0, W1, A1{2}] = 12
    SCHEDB;
    WAITVM(2);               // retire A0+W1 -> wB; [A1{2}]
    G2_LOADW(wA, 2);         // [A1{2}, W2{8}] = 10
    SCHEDB;
    WAITLGKM0;
    BARRIER;
    SCHEDB;

    for (int k = 0; k < NK; k += 2) {
        G2_STEP(k,     wB, 0);
        G2_STEP(k + 1, wA, 1);
    }
    WAITVM(0);

    int crow = (l >> 4) << 2;
    int ccol = l & 15;
    #pragma unroll
    for (int m = 0; m < 4; ++m) {
        #pragma unroll
        for (int reg = 0; reg < 4; ++reg) {
            int r = wr + m * 16 + crow + reg;
            if (r < nrows) {
                atomicAdd(&out[(size_t)rows[rs + r] * HDIM + n0 + wc + ccol], acc[m][reg]);
            }
        }
    }
    #undef G2_LOADW
    #undef G2_WRITEW
    #undef G2_DMA
    #undef G2_MFMA
    #undef G2_STEP
}

extern "C" void kernel_launch(void* const* d_in, const int* in_sizes, int n_in,
                              void* d_out, int out_size, void* d_ws, size_t ws_size,
                              hipStream_t stream) {
    const float* x    = (const float*)d_in[0];
    const float* Wr   = (const float*)d_in[1];
    const float* bias = (const float*)d_in[2];
    const float* Wg   = (const float*)d_in[3];
    const float* Wu   = (const float*)d_in[4];
    const float* Wd   = (const float*)d_in[5];
    const float* sWg  = (const float*)d_in[6];
    const float* sWu  = (const float*)d_in[7];
    const float* sWd  = (const float*)d_in[8];
    float* out = (float*)d_out;

    char* p = (char*)d_ws;
    int*   counts = (int*)p;                 p += 256;
    int*   offs   = (int*)p;                 p += 256;
    int*   cursor = (int*)p;                 p += 256;
    int4*  tiles  = (int4*)p;                p += TM * sizeof(int4);
    int*   idxtok = (int*)p;                 p += (size_t)T_TOK * 2 * sizeof(int);
    float* wtok   = (float*)p;               p += (size_t)T_TOK * 2 * sizeof(float);
    int*   rows   = (int*)p;                 p += (size_t)NASSIGN * sizeof(int);
    float* wrow   = (float*)p;               p += (size_t)NASSIGN * sizeof(float);
    unsigned short* act = (unsigned short*)p; p += (size_t)NASSIGN * IDIM * sizeof(unsigned short);
    unsigned short* xbf = (unsigned short*)p; // 8.4MB

    hipMemsetAsync(counts, 0, 256, stream);
    hipMemsetAsync(d_out, 0, (size_t)out_size * sizeof(float), stream);

    k_cvt<<<dim3(T_TOK * HDIM / 1024), dim3(256), 0, stream>>>(x, xbf);
    k_router<<<dim3(T_TOK), dim3(256), 0, stream>>>(x, Wr, bias, wtok, idxtok, counts);
    k_scan<<<dim3(1), dim3(64), 0, stream>>>(counts, offs, cursor, tiles);
    k_scatter<<<dim3((T_TOK + 255) / 256), dim3(256), 0, stream>>>(idxtok, wtok, cursor, offs, rows, wrow);
    k_gemm1<<<dim3(G1_NWG), dim3(512), 0, stream>>>(xbf, Wg, Wu, sWg, sWu, tiles, rows, wrow, act);
    k_gemm2<<<dim3(G2_NWG), dim3(512), 0, stream>>>(act, Wd, sWd, tiles, rows, out);
}